// Round 10
// baseline (1049.184 us; speedup 1.0000x reference)
//
#include <hip/hip_runtime.h>

#define N_NODES_C 100000
#define N_REL_C 5
#define N_TOT (N_REL_C * N_NODES_C)
#define FEAT 128
#define KTOT 768        // virtual K = 128 (root) + 5*128 (relations)
#define BM 128          // GEMM block rows
#define GBK 64          // GEMM K-tile
#define NSWEEP 4        // fill_csr key-range sweeps

typedef __attribute__((ext_vector_type(8))) short bf16x8;
typedef __attribute__((ext_vector_type(4))) float f32x4;

__device__ inline unsigned short f2bf(float f) {
    union { float f; unsigned int u; } v; v.f = f;
    return (unsigned short)((v.u + 0x7FFFu + ((v.u >> 16) & 1u)) >> 16);
}

// packed f32x2 -> bf16x2 (RNE) in one VALU instr
__device__ __forceinline__ unsigned int cvt_pk_bf16(float lo, float hi) {
    unsigned int r;
    asm("v_cvt_pk_bf16_f32 %0, %1, %2" : "=v"(r) : "v"(lo), "v"(hi));
    return r;
}

// async 16B global->LDS: lds dest = wave-uniform base + lane*16 (m97 pattern)
__device__ __forceinline__ void g2l16(const void* g, void* l) {
    __builtin_amdgcn_global_load_lds((const __attribute__((address_space(1))) unsigned int*)g,
                                     (__attribute__((address_space(3))) unsigned int*)l,
                                     16, 0, 0);
}

// unpack 8 bf16 (uint4) and add into 8 f32 accumulators
__device__ __forceinline__ void acc8(float (&a)[8], uint4 u) {
    union { unsigned int u; float f; } t;
    t.u = u.x << 16;         a[0] += t.f;
    t.u = u.x & 0xFFFF0000u; a[1] += t.f;
    t.u = u.y << 16;         a[2] += t.f;
    t.u = u.y & 0xFFFF0000u; a[3] += t.f;
    t.u = u.z << 16;         a[4] += t.f;
    t.u = u.z & 0xFFFF0000u; a[5] += t.f;
    t.u = u.w << 16;         a[6] += t.f;
    t.u = u.w & 0xFFFF0000u; a[7] += t.f;
}

// ---------------------------------------------------------------------------
// preprocessing: counts, inv, scan -> CSR grouped by (relation, dst)
// ---------------------------------------------------------------------------
__global__ __launch_bounds__(256) void count_edges(const int* __restrict__ dst,
                                                   const int* __restrict__ et,
                                                   int* __restrict__ cnt, int E) {
    int e = blockIdx.x * 256 + threadIdx.x;
    if (e < E) atomicAdd(&cnt[et[e] * N_NODES_C + dst[e]], 1);
}

__global__ __launch_bounds__(256) void make_inv(const int* __restrict__ cnt,
                                                float* __restrict__ inv, int n) {
    int i = blockIdx.x * 256 + threadIdx.x;
    if (i < n) inv[i] = 1.0f / (float)(cnt[i] > 1 ? cnt[i] : 1);
}

__global__ __launch_bounds__(256) void scan_block(const int* __restrict__ cnt,
                                                  int* __restrict__ rowptr,
                                                  int* __restrict__ bsum, int n) {
    __shared__ int sh[256];
    int tid = threadIdx.x;
    int i = blockIdx.x * 256 + tid;
    int v = (i < n) ? cnt[i] : 0;
    sh[tid] = v;
    __syncthreads();
#pragma unroll
    for (int o = 1; o < 256; o <<= 1) {
        int t = (tid >= o) ? sh[tid - o] : 0;
        __syncthreads();
        sh[tid] += t;
        __syncthreads();
    }
    if (i < n) rowptr[i] = sh[tid] - v;
    if (tid == 255) bsum[blockIdx.x] = sh[255];
}

__global__ __launch_bounds__(256) void scan_bsum(int* __restrict__ bsum, int nb) {
    __shared__ int sh[256];
    __shared__ int carry;
    int tid = threadIdx.x;
    if (tid == 0) carry = 0;
    __syncthreads();
    for (int base = 0; base < nb; base += 256) {
        int i = base + tid;
        int v = (i < nb) ? bsum[i] : 0;
        sh[tid] = v;
        __syncthreads();
#pragma unroll
        for (int o = 1; o < 256; o <<= 1) {
            int t = (tid >= o) ? sh[tid - o] : 0;
            __syncthreads();
            sh[tid] += t;
            __syncthreads();
        }
        int excl = sh[tid] - v + carry;
        int chunk_total = sh[255];
        __syncthreads();
        if (i < nb) bsum[i] = excl;
        if (tid == 0) carry += chunk_total;
        __syncthreads();
    }
}

__global__ __launch_bounds__(256) void scan_add(int* __restrict__ rowptr,
                                                const int* __restrict__ bsum,
                                                int n, int Etot) {
    int i = blockIdx.x * 256 + threadIdx.x;
    if (i < n) rowptr[i] += bsum[blockIdx.x];
    if (i == 0) rowptr[n] = Etot;
}

__global__ __launch_bounds__(256) void fill_csr_sweep(const int* __restrict__ src,
                                                      const int* __restrict__ dst,
                                                      const int* __restrict__ et,
                                                      int* __restrict__ cursor,
                                                      int* __restrict__ esrc,
                                                      int E, int klo, int khi) {
    int e = blockIdx.x * 256 + threadIdx.x;
    if (e < E) {
        int key = et[e] * N_NODES_C + dst[e];
        if ((unsigned)(key - klo) < (unsigned)(khi - klo)) {
            int pos = atomicAdd(&cursor[key], 1);
            esrc[pos] = src[e];
        }
    }
}

// ---------------------------------------------------------------------------
// conversions to bf16
// ---------------------------------------------------------------------------
__global__ __launch_bounds__(256) void convert_x(const float* __restrict__ x,
                                                 unsigned short* __restrict__ xb, int n4) {
    int i = blockIdx.x * 256 + threadIdx.x;
    if (i >= n4) return;
    float4 v = ((const float4*)x)[i];
    ushort4 o;
    o.x = f2bf(v.x); o.y = f2bf(v.y); o.z = f2bf(v.z); o.w = f2bf(v.w);
    ((ushort4*)xb)[i] = o;
}

// Bt[c][kv] (col-major over virtual K): kv<128 -> root[kv][c]; else W[r][kk][c]
__global__ __launch_bounds__(256) void convert_w(const float* __restrict__ root,
                                                 const float* __restrict__ W,
                                                 unsigned short* __restrict__ Bt) {
    int idx = blockIdx.x * 256 + threadIdx.x;
    if (idx >= FEAT * KTOT) return;
    int c = idx / KTOT;
    int kv = idx - c * KTOT;
    float val;
    if (kv < FEAT) {
        val = root[kv * FEAT + c];
    } else {
        int r = (kv - FEAT) >> 7;
        int kk = (kv - FEAT) & 127;
        val = W[((size_t)r * FEAT + kk) * FEAT + c];
    }
    Bt[idx] = f2bf(val);
}

// ---------------------------------------------------------------------------
// FUSED gather+GEMM: C[n][:] = relu( [hb[n] | mean_r(hb[src])...] @ B + bias )
// v8 rationale (R7 counters): gather hit an L2-miss fabric ceiling (4.15 TB/s,
// FETCH 187MB = hb x 8 XCDs = structural floor). Remaining lever is traffic:
// the 125MB agg HBM write + 128MB GEMM re-read round-trip exists only because
// gather/GEMM were separate kernels. Fuse: per relation, gather means directly
// into a 32KB LDS A-panel, then run the 2 MFMA K-steps from it.
//   Root phase: unchanged m97 staging (GBK=64 tile, chunk^(row&7) swizzle).
//   Relation A-panel: [128 rows][16 chunks of 16B]; writer chunk = seg^(n&15),
//   reader chunk = (kt*8+h*4+lq)^(row&15) -> consistent, 2-way banks (free).
//   LDS 48KB -> 3 blocks/CU; gather latency overlaps other blocks' MFMA.
// ---------------------------------------------------------------------------
__global__ __launch_bounds__(256, 3) void rgcn_fused(const unsigned short* __restrict__ hb,
                                                     const unsigned short* __restrict__ Bt,
                                                     const int* __restrict__ esrc,
                                                     const int* __restrict__ rowptr,
                                                     const float* __restrict__ inv,
                                                     const float* __restrict__ bias,
                                                     float* __restrict__ outf,
                                                     unsigned short* __restrict__ outb) {
    __shared__ __align__(16) unsigned short Ap[BM * FEAT];   // 32 KB
    __shared__ __align__(16) unsigned short Bs[FEAT * GBK];  // 16 KB

    const int tid = threadIdx.x;
    const int w = tid >> 6, lane = tid & 63;
    const int wr = w >> 1, wc = w & 1;
    const int lm = lane & 15, lq = lane >> 4;
    const int qw = tid >> 4, seg = tid & 15;
    const int brow0 = blockIdx.x * BM;

    f32x4 acc[4][4];
#pragma unroll
    for (int i = 0; i < 4; i++)
#pragma unroll
        for (int j = 0; j < 4; j++) acc[i][j] = (f32x4){0.f, 0.f, 0.f, 0.f};

    // staging geometry (m97): instr i of wave w covers chunk ids
    // cid = (w*4+i)*64 + lane; row = cid>>3, c = cid&7; source swizzled c^(row&7)
    size_t hboff[4];
    size_t boff[4];
    int ldsbase[4];
#pragma unroll
    for (int i = 0; i < 4; i++) {
        int cid = (w * 4 + i) * 64 + lane;
        int row = cid >> 3;
        int cs = (cid & 7) ^ (row & 7);
        int gr = brow0 + row;
        if (gr >= N_NODES_C) gr = N_NODES_C - 1;
        hboff[i] = ((size_t)gr << 7) + cs * 8;
        boff[i]  = (size_t)row * KTOT + cs * 8;   // row doubles as col for B
        ldsbase[i] = ((w * 4 + i) * 64) * 8;
    }

    // ---- root: kb = 0, 64 (A from hb, staged into first 16KB of Ap) ----
    for (int kb = 0; kb < FEAT; kb += GBK) {
        __syncthreads();
#pragma unroll
        for (int i = 0; i < 4; i++)
            g2l16(hb + hboff[i] + kb, &Ap[ldsbase[i]]);
#pragma unroll
        for (int i = 0; i < 4; i++)
            g2l16(Bt + boff[i] + kb, &Bs[ldsbase[i]]);
        __syncthreads();

#pragma unroll
        for (int h = 0; h < 2; h++) {
            bf16x8 af[4], bf[4];
#pragma unroll
            for (int t = 0; t < 4; t++) {
                int row = wr * 64 + t * 16 + lm;
                int ca = (h * 4 + lq) ^ (row & 7);
                af[t] = *(const bf16x8*)&Ap[row * GBK + ca * 8];
                int col = wc * 64 + t * 16 + lm;
                int cb = (h * 4 + lq) ^ (col & 7);
                bf[t] = *(const bf16x8*)&Bs[col * GBK + cb * 8];
            }
#pragma unroll
            for (int i = 0; i < 4; i++)
#pragma unroll
                for (int j = 0; j < 4; j++)
                    acc[i][j] = __builtin_amdgcn_mfma_f32_16x16x32_bf16(af[i], bf[j], acc[i][j], 0, 0, 0);
        }
    }

    // ---- relations ----
    for (int r = 0; r < N_REL_C; r++) {
        const int kb0 = FEAT + r * FEAT;
        __syncthreads();             // prev compute done: Ap + Bs free
        // issue B tile (kt=0) early; lands while we gather
#pragma unroll
        for (int i = 0; i < 4; i++)
            g2l16(Bt + boff[i] + kb0, &Bs[ldsbase[i]]);

        // gather means: each quarter-wave handles 8 nodes (n = j*16+qw)
        for (int j = 0; j < 8; j++) {
            int n = j * 16 + qw;
            int node = brow0 + n;
            if (node < N_NODES_C) {
                int idx = r * N_NODES_C + node;
                int lo = rowptr[idx];
                int hi = rowptr[idx + 1];
                float a0[8], a1[8];
#pragma unroll
                for (int k = 0; k < 8; k++) { a0[k] = 0.f; a1[k] = 0.f; }
                const unsigned short* hseg = hb + seg * 8;
                int e = lo;
                for (; e + 2 <= hi; e += 2) {
                    int s0 = esrc[e];
                    int s1 = esrc[e + 1];
                    uint4 u0 = *(const uint4*)(hseg + ((size_t)s0 << 7));
                    uint4 u1 = *(const uint4*)(hseg + ((size_t)s1 << 7));
                    acc8(a0, u0);
                    acc8(a1, u1);
                }
                if (e < hi) {
                    int s = esrc[e];
                    uint4 u = *(const uint4*)(hseg + ((size_t)s << 7));
                    acc8(a0, u);
                }
                float sc = inv[idx];
                uint4 o;
                o.x = cvt_pk_bf16((a0[0] + a1[0]) * sc, (a0[1] + a1[1]) * sc);
                o.y = cvt_pk_bf16((a0[2] + a1[2]) * sc, (a0[3] + a1[3]) * sc);
                o.z = cvt_pk_bf16((a0[4] + a1[4]) * sc, (a0[5] + a1[5]) * sc);
                o.w = cvt_pk_bf16((a0[6] + a1[6]) * sc, (a0[7] + a1[7]) * sc);
                int ws = seg ^ (n & 15);
                *(uint4*)&Ap[n * FEAT + ws * 8] = o;
            }
        }
        __syncthreads();             // Ap written + Bs(kt0) arrived

#pragma unroll
        for (int kt = 0; kt < 2; kt++) {
            if (kt == 1) {
                __syncthreads();     // Bs(kt0) reads done
#pragma unroll
                for (int i = 0; i < 4; i++)
                    g2l16(Bt + boff[i] + kb0 + GBK, &Bs[ldsbase[i]]);
                __syncthreads();     // Bs(kt1) arrived
            }
#pragma unroll
            for (int h = 0; h < 2; h++) {
                bf16x8 af[4], bf[4];
#pragma unroll
                for (int t = 0; t < 4; t++) {
                    int row = wr * 64 + t * 16 + lm;
                    int cc = kt * 8 + h * 4 + lq;
                    int cs2 = cc ^ (row & 15);
                    af[t] = *(const bf16x8*)&Ap[row * FEAT + cs2 * 8];
                    int col = wc * 64 + t * 16 + lm;
                    int cb = (h * 4 + lq) ^ (col & 7);
                    bf[t] = *(const bf16x8*)&Bs[col * GBK + cb * 8];
                }
#pragma unroll
                for (int i = 0; i < 4; i++)
#pragma unroll
                    for (int j = 0; j < 4; j++)
                        acc[i][j] = __builtin_amdgcn_mfma_f32_16x16x32_bf16(af[i], bf[j], acc[i][j], 0, 0, 0);
            }
        }
    }

    // ---- epilogue ----
    float bcol[4];
#pragma unroll
    for (int j = 0; j < 4; j++) bcol[j] = bias[wc * 64 + j * 16 + lm];

#pragma unroll
    for (int i = 0; i < 4; i++) {
#pragma unroll
        for (int reg = 0; reg < 4; reg++) {
            int lr = brow0 + wr * 64 + i * 16 + lq * 4 + reg;
            if (lr < N_NODES_C) {
                size_t grow = (size_t)lr << 7;
#pragma unroll
                for (int j = 0; j < 4; j++) {
                    float v = acc[i][j][reg] + bcol[j];
                    v = fmaxf(v, 0.f);
                    int col = wc * 64 + j * 16 + lm;
                    if (outf) outf[grow + col] = v;
                    else outb[grow + col] = f2bf(v);
                }
            }
        }
    }
}

// ---------------------------------------------------------------------------
extern "C" void kernel_launch(void* const* d_in, const int* in_sizes, int n_in,
                              void* d_out, int out_size, void* d_ws, size_t ws_size,
                              hipStream_t stream) {
    const float* x = (const float*)d_in[0];
    const int* ei  = (const int*)d_in[1];
    const int* et  = (const int*)d_in[2];
    const int E = in_sizes[2];
    const int* src  = ei;
    const int* dstp = ei + E;

    // workspace layout (agg buffer no longer needed -- fused kernel):
    //   inv    @ 0           (2,000,000)
    //   rowptr @ 2,097,152   (2,000,004)
    //   esrc   @ 4,194,304   (6,400,000)
    //   xbA    @ 10,616,832  (25,600,000)
    //   xbB    @ 36,306,944  (25,600,000)
    //   scratch@ 61,997,056  [cnt/cursor/bsum]
    //   Bt     @ 70,000,000  (589,824)
    char* ws = (char*)d_ws;
    float* inv             = (float*)ws;
    int*   rowptr          = (int*)(ws + 2097152);
    int*   esrc            = (int*)(ws + 4194304);
    unsigned short* xbA    = (unsigned short*)(ws + 10616832);
    unsigned short* xbB    = (unsigned short*)(ws + 36306944);
    int*   cnt    = (int*)(ws + 61997056);
    int*   cursor = (int*)(ws + 61997056 + 2097152);
    int*   bsum   = (int*)(ws + 61997056 + 4194304);
    unsigned short* BtAll  = (unsigned short*)(ws + 70000000);

    const int nscan_blocks = (N_TOT + 255) / 256;

    hipMemsetAsync(cnt, 0, (size_t)N_TOT * 4, stream);
    count_edges<<<(E + 255) / 256, 256, 0, stream>>>(dstp, et, cnt, E);
    make_inv<<<(N_TOT + 255) / 256, 256, 0, stream>>>(cnt, inv, N_TOT);
    scan_block<<<nscan_blocks, 256, 0, stream>>>(cnt, rowptr, bsum, N_TOT);
    scan_bsum<<<1, 256, 0, stream>>>(bsum, nscan_blocks);
    scan_add<<<nscan_blocks, 256, 0, stream>>>(rowptr, bsum, N_TOT, E);
    hipMemcpyAsync(cursor, rowptr, (size_t)N_TOT * 4, hipMemcpyDeviceToDevice, stream);
    {
        const int kspan = N_TOT / NSWEEP;
        for (int s = 0; s < NSWEEP; s++)
            fill_csr_sweep<<<(E + 255) / 256, 256, 0, stream>>>(src, dstp, et, cursor,
                                                                esrc, E, s * kspan,
                                                                (s + 1) * kspan);
    }

    const int n4 = N_NODES_C * FEAT / 4;
    convert_x<<<(n4 + 255) / 256, 256, 0, stream>>>(x, xbA, n4);

    const float* Wp[3] = {(const float*)d_in[3], (const float*)d_in[6], (const float*)d_in[9]};
    const float* Rp[3] = {(const float*)d_in[4], (const float*)d_in[7], (const float*)d_in[10]};
    const float* Bp[3] = {(const float*)d_in[5], (const float*)d_in[8], (const float*)d_in[11]};

    const int nw = FEAT * KTOT;
    for (int l = 0; l < 3; l++)
        convert_w<<<(nw + 255) / 256, 256, 0, stream>>>(Rp[l], Wp[l],
                                                        BtAll + (size_t)l * nw);

    const int grid = (N_NODES_C + BM - 1) / BM;   // 782

    // layer dataflow (bf16 ping-pong): xbA -> xbB -> xbA -> d_out(fp32)
    for (int l = 0; l < 3; l++) {
        const unsigned short* hin = (l == 1) ? xbB : xbA;
        unsigned short* outb = (l == 0) ? xbB : ((l == 1) ? xbA : nullptr);
        float* outf = (l == 2) ? (float*)d_out : nullptr;
        rgcn_fused<<<grid, 256, 0, stream>>>(hin, BtAll + (size_t)l * nw, esrc,
                                             rowptr, inv, Bp[l], outf, outb);
    }
}

// Round 12
// 651.080 us; speedup vs baseline: 1.6115x; 1.6115x over previous
//
#include <hip/hip_runtime.h>

#define N_NODES_C 100000
#define N_REL_C 5
#define N_TOT (N_REL_C * N_NODES_C)
#define FEAT 128
#define KTOT 768        // virtual K = 128 (root) + 5*128 (relations)
#define BM 128          // GEMM block rows
#define GBK 64          // GEMM K-tile
#define NPART 2048      // blocks for XCD-partitioned count/fill (multiple of 8)

typedef __attribute__((ext_vector_type(8))) short bf16x8;
typedef __attribute__((ext_vector_type(4))) float f32x4;

__device__ inline unsigned short f2bf(float f) {
    union { float f; unsigned int u; } v; v.f = f;
    return (unsigned short)((v.u + 0x7FFFu + ((v.u >> 16) & 1u)) >> 16);
}

// packed f32x2 -> bf16x2 (RNE) in one VALU instr
__device__ __forceinline__ unsigned int cvt_pk_bf16(float lo, float hi) {
    unsigned int r;
    asm("v_cvt_pk_bf16_f32 %0, %1, %2" : "=v"(r) : "v"(lo), "v"(hi));
    return r;
}

// async 16B global->LDS: lds dest = wave-uniform base + lane*16 (m97 pattern)
__device__ __forceinline__ void g2l16(const void* g, void* l) {
    __builtin_amdgcn_global_load_lds((const __attribute__((address_space(1))) unsigned int*)g,
                                     (__attribute__((address_space(3))) unsigned int*)l,
                                     16, 0, 0);
}

// unpack 8 bf16 (uint4) and add into 8 f32 accumulators
__device__ __forceinline__ void acc8(float (&a)[8], uint4 u) {
    union { unsigned int u; float f; } t;
    t.u = u.x << 16;         a[0] += t.f;
    t.u = u.x & 0xFFFF0000u; a[1] += t.f;
    t.u = u.y << 16;         a[2] += t.f;
    t.u = u.y & 0xFFFF0000u; a[3] += t.f;
    t.u = u.z << 16;         a[4] += t.f;
    t.u = u.z & 0xFFFF0000u; a[5] += t.f;
    t.u = u.w << 16;         a[6] += t.f;
    t.u = u.w & 0xFFFF0000u; a[7] += t.f;
}

// ---------------------------------------------------------------------------
// preprocessing: counts, inv, scan -> CSR grouped by (relation, dst)
// XCD-partitioned count/fill (v10): blocks dispatch round-robin over the 8
// XCDs, so blockIdx&7 ~ XCD id. Class c owns keys with key>>16 == c: every
// block scans all edges (12.8MB, L2/L3 read - cheap) but only touches its own
// 256KB cnt/cursor window and ~E/8 contiguous esrc window -> atomics are
// XCD-local (no line bounce) and each esrc line is written back once. This is
// the spatial fix for R3's 108MB partial-line bounce that temporal sweeping
// (R5/R7) provably could not deliver. Correct under any blockIdx->XCD mapping.
// ---------------------------------------------------------------------------
__global__ __launch_bounds__(256) void count_part(const int* __restrict__ dst,
                                                  const int* __restrict__ et,
                                                  int* __restrict__ cnt, int E) {
    int cls = blockIdx.x & 7;
    int base = (blockIdx.x >> 3) * 256 + threadIdx.x;
    int stride = (gridDim.x >> 3) << 8;
    for (int e = base; e < E; e += stride) {
        int key = et[e] * N_NODES_C + dst[e];
        if ((key >> 16) == cls) atomicAdd(&cnt[key], 1);
    }
}

__global__ __launch_bounds__(256) void fill_part(const int* __restrict__ src,
                                                 const int* __restrict__ dst,
                                                 const int* __restrict__ et,
                                                 int* __restrict__ cursor,
                                                 int* __restrict__ esrc, int E) {
    int cls = blockIdx.x & 7;
    int base = (blockIdx.x >> 3) * 256 + threadIdx.x;
    int stride = (gridDim.x >> 3) << 8;
    for (int e = base; e < E; e += stride) {
        int key = et[e] * N_NODES_C + dst[e];
        if ((key >> 16) == cls) {
            int pos = atomicAdd(&cursor[key], 1);
            esrc[pos] = src[e];
        }
    }
}

__global__ __launch_bounds__(256) void make_inv(const int* __restrict__ cnt,
                                                float* __restrict__ inv, int n) {
    int i = blockIdx.x * 256 + threadIdx.x;
    if (i < n) inv[i] = 1.0f / (float)(cnt[i] > 1 ? cnt[i] : 1);
}

__global__ __launch_bounds__(256) void scan_block(const int* __restrict__ cnt,
                                                  int* __restrict__ rowptr,
                                                  int* __restrict__ bsum, int n) {
    __shared__ int sh[256];
    int tid = threadIdx.x;
    int i = blockIdx.x * 256 + tid;
    int v = (i < n) ? cnt[i] : 0;
    sh[tid] = v;
    __syncthreads();
#pragma unroll
    for (int o = 1; o < 256; o <<= 1) {
        int t = (tid >= o) ? sh[tid - o] : 0;
        __syncthreads();
        sh[tid] += t;
        __syncthreads();
    }
    if (i < n) rowptr[i] = sh[tid] - v;
    if (tid == 255) bsum[blockIdx.x] = sh[255];
}

__global__ __launch_bounds__(256) void scan_bsum(int* __restrict__ bsum, int nb) {
    __shared__ int sh[256];
    __shared__ int carry;
    int tid = threadIdx.x;
    if (tid == 0) carry = 0;
    __syncthreads();
    for (int base = 0; base < nb; base += 256) {
        int i = base + tid;
        int v = (i < nb) ? bsum[i] : 0;
        sh[tid] = v;
        __syncthreads();
#pragma unroll
        for (int o = 1; o < 256; o <<= 1) {
            int t = (tid >= o) ? sh[tid - o] : 0;
            __syncthreads();
            sh[tid] += t;
            __syncthreads();
        }
        int excl = sh[tid] - v + carry;
        int chunk_total = sh[255];
        __syncthreads();
        if (i < nb) bsum[i] = excl;
        if (tid == 0) carry += chunk_total;
        __syncthreads();
    }
}

__global__ __launch_bounds__(256) void scan_add(int* __restrict__ rowptr,
                                                const int* __restrict__ bsum,
                                                int n, int Etot) {
    int i = blockIdx.x * 256 + threadIdx.x;
    if (i < n) rowptr[i] += bsum[blockIdx.x];
    if (i == 0) rowptr[n] = Etot;
}

// ---------------------------------------------------------------------------
// conversions to bf16
// ---------------------------------------------------------------------------
__global__ __launch_bounds__(256) void convert_x(const float* __restrict__ x,
                                                 unsigned short* __restrict__ xb, int n4) {
    int i = blockIdx.x * 256 + threadIdx.x;
    if (i >= n4) return;
    float4 v = ((const float4*)x)[i];
    ushort4 o;
    o.x = f2bf(v.x); o.y = f2bf(v.y); o.z = f2bf(v.z); o.w = f2bf(v.w);
    ((ushort4*)xb)[i] = o;
}

// Bt[c][kv] (col-major over virtual K): kv<128 -> root[kv][c]; else W[r][kk][c]
__global__ __launch_bounds__(256) void convert_w(const float* __restrict__ root,
                                                 const float* __restrict__ W,
                                                 unsigned short* __restrict__ Bt) {
    int idx = blockIdx.x * 256 + threadIdx.x;
    if (idx >= FEAT * KTOT) return;
    int c = idx / KTOT;
    int kv = idx - c * KTOT;
    float val;
    if (kv < FEAT) {
        val = root[kv * FEAT + c];
    } else {
        int r = (kv - FEAT) >> 7;
        int kk = (kv - FEAT) & 127;
        val = W[((size_t)r * FEAT + kk) * FEAT + c];
    }
    Bt[idx] = f2bf(val);
}

// ---------------------------------------------------------------------------
// gather: agg[r][local][:] = mean over CSR[r][node] of hb[src][:]  (bf16 out)
// v5 (R7-verified, 77us = L2-miss fabric floor: FETCH 187MB = hb x 8 XCDs):
// quarter-wave per (relation, node), edge loop unrolled x4, cvt_pk epilogue.
// ---------------------------------------------------------------------------
__global__ __launch_bounds__(256) void gather_mean(const unsigned short* __restrict__ hb,
                                                   const int* __restrict__ esrc,
                                                   const int* __restrict__ rowptr,
                                                   const float* __restrict__ inv,
                                                   unsigned short* __restrict__ agg,
                                                   int chunk0, int CL) {
    int qw = threadIdx.x >> 4;       // 0..15 quarter-waves per block
    int seg = threadIdx.x & 15;      // feats [seg*8, seg*8+8)
    int local = blockIdx.x * 16 + qw;
    if (local >= CL) return;
    int r = blockIdx.y;
    int node = chunk0 + local;
    int lo = rowptr[r * N_NODES_C + node];
    int hi = rowptr[r * N_NODES_C + node + 1];

    float a0[8], a1[8];
#pragma unroll
    for (int j = 0; j < 8; j++) { a0[j] = 0.f; a1[j] = 0.f; }

    const unsigned short* hseg = hb + seg * 8;

    int e = lo;
    for (; e + 4 <= hi; e += 4) {
        int s0 = esrc[e];
        int s1 = esrc[e + 1];
        int s2 = esrc[e + 2];
        int s3 = esrc[e + 3];
        uint4 u0 = *(const uint4*)(hseg + ((size_t)s0 << 7));
        uint4 u1 = *(const uint4*)(hseg + ((size_t)s1 << 7));
        uint4 u2 = *(const uint4*)(hseg + ((size_t)s2 << 7));
        uint4 u3 = *(const uint4*)(hseg + ((size_t)s3 << 7));
        acc8(a0, u0);
        acc8(a1, u1);
        acc8(a0, u2);
        acc8(a1, u3);
    }
    if (e + 2 <= hi) {
        int s0 = esrc[e];
        int s1 = esrc[e + 1];
        uint4 u0 = *(const uint4*)(hseg + ((size_t)s0 << 7));
        uint4 u1 = *(const uint4*)(hseg + ((size_t)s1 << 7));
        acc8(a0, u0);
        acc8(a1, u1);
        e += 2;
    }
    if (e < hi) {
        int s = esrc[e];
        uint4 u = *(const uint4*)(hseg + ((size_t)s << 7));
        acc8(a0, u);
    }

    float sc = inv[r * N_NODES_C + node];
    uint4 o;
    o.x = cvt_pk_bf16((a0[0] + a1[0]) * sc, (a0[1] + a1[1]) * sc);
    o.y = cvt_pk_bf16((a0[2] + a1[2]) * sc, (a0[3] + a1[3]) * sc);
    o.z = cvt_pk_bf16((a0[4] + a1[4]) * sc, (a0[5] + a1[5]) * sc);
    o.w = cvt_pk_bf16((a0[6] + a1[6]) * sc, (a0[7] + a1[7]) * sc);
    *(uint4*)(agg + (((size_t)r * CL + local) << 7) + seg * 8) = o;
}

// ---------------------------------------------------------------------------
// MFMA GEMM (m97-style): C[n][0:128] = relu( A_virt[n][0:768] @ B + bias )
//   A_virt k<128 -> hb[node][k]; k>=128 -> agg[r][local][k%128] (pre-scaled means)
// BK=64, global_load_lds(16B) staging into unpadded LDS with chunk-XOR swizzle
// (c ^ (row&7)); reader applies same XOR -> 2-way bank aliasing (free, m136).
// Block 128x128, 4 waves 2x2, wave tile 64x64 (4x4 MFMA 16x16x32 tiles).
// ---------------------------------------------------------------------------
__global__ __launch_bounds__(256) void rgcn_gemm(const unsigned short* __restrict__ hb,
                                                 const unsigned short* __restrict__ agg,
                                                 const unsigned short* __restrict__ Bt,
                                                 const float* __restrict__ bias,
                                                 float* __restrict__ outf,
                                                 unsigned short* __restrict__ outb,
                                                 int chunk0, int CL) {
    __shared__ unsigned short As[BM * GBK];    // 16 KB
    __shared__ unsigned short Bs[FEAT * GBK];  // 16 KB

    const int tid = threadIdx.x;
    const int w = tid >> 6, lane = tid & 63;
    const int wr = w >> 1, wc = w & 1;
    const int lm = lane & 15, lq = lane >> 4;
    const int brow0 = blockIdx.x * BM;

    f32x4 acc[4][4];
#pragma unroll
    for (int i = 0; i < 4; i++)
#pragma unroll
        for (int j = 0; j < 4; j++) acc[i][j] = (f32x4){0.f, 0.f, 0.f, 0.f};

    // staging geometry: 1024 16B-chunks per tile; instr i of wave w covers
    // chunk ids cid = (w*4+i)*64 + lane; cid -> (row = cid>>3, c = cid&7).
    // source chunk is XOR-swizzled: cs = c ^ (row&7).
    size_t hboff[4];   // hb row offset + swizzled chunk (add kb)
    size_t aggoff[4];  // agg row offset + swizzled chunk (add rel term)
    size_t boff[4];    // Bt col offset + swizzled chunk (add kb)
    int ldsbase[4];    // wave-uniform LDS ushort base per instr
#pragma unroll
    for (int i = 0; i < 4; i++) {
        int cid = (w * 4 + i) * 64 + lane;
        int row = cid >> 3;
        int cs = (cid & 7) ^ (row & 7);
        int gr = brow0 + row;
        if (gr >= CL) gr = CL - 1;
        hboff[i]  = ((size_t)(chunk0 + gr) << 7) + cs * 8;
        aggoff[i] = ((size_t)gr << 7) + cs * 8;
        boff[i]   = (size_t)row * KTOT + cs * 8;   // row doubles as col for B
        ldsbase[i] = ((w * 4 + i) * 64) * 8;
    }

    for (int kb = 0; kb < KTOT; kb += GBK) {
        __syncthreads();   // prev-iter LDS reads done before overwrite
        if (kb < FEAT) {
#pragma unroll
            for (int i = 0; i < 4; i++)
                g2l16(hb + hboff[i] + kb, &As[ldsbase[i]]);
        } else {
            size_t reloff = (((size_t)((kb - FEAT) >> 7)) * CL << 7) + (size_t)((kb - FEAT) & 127);
#pragma unroll
            for (int i = 0; i < 4; i++)
                g2l16(agg + aggoff[i] + reloff, &As[ldsbase[i]]);
        }
#pragma unroll
        for (int i = 0; i < 4; i++)
            g2l16(Bt + boff[i] + kb, &Bs[ldsbase[i]]);
        __syncthreads();   // compiler emits vmcnt(0) drain before barrier

#pragma unroll
        for (int h = 0; h < 2; h++) {
            bf16x8 af[4], bf[4];
#pragma unroll
            for (int t = 0; t < 4; t++) {
                int row = wr * 64 + t * 16 + lm;
                int ca = (h * 4 + lq) ^ (row & 7);
                af[t] = *(const bf16x8*)&As[row * GBK + ca * 8];
                int col = wc * 64 + t * 16 + lm;
                int cb = (h * 4 + lq) ^ (col & 7);
                bf[t] = *(const bf16x8*)&Bs[col * GBK + cb * 8];
            }
#pragma unroll
            for (int i = 0; i < 4; i++)
#pragma unroll
                for (int j = 0; j < 4; j++)
                    acc[i][j] = __builtin_amdgcn_mfma_f32_16x16x32_bf16(af[i], bf[j], acc[i][j], 0, 0, 0);
        }
    }

    float bcol[4];
#pragma unroll
    for (int j = 0; j < 4; j++) bcol[j] = bias[wc * 64 + j * 16 + lm];

#pragma unroll
    for (int i = 0; i < 4; i++) {
#pragma unroll
        for (int reg = 0; reg < 4; reg++) {
            int lr = brow0 + wr * 64 + i * 16 + lq * 4 + reg;
            if (lr < CL) {
                size_t grow = (size_t)(chunk0 + lr) << 7;
#pragma unroll
                for (int j = 0; j < 4; j++) {
                    float v = acc[i][j][reg] + bcol[j];
                    v = fmaxf(v, 0.f);
                    int col = wc * 64 + j * 16 + lm;
                    if (outf) outf[grow + col] = v;
                    else outb[grow + col] = f2bf(v);
                }
            }
        }
    }
}

// ---------------------------------------------------------------------------
extern "C" void kernel_launch(void* const* d_in, const int* in_sizes, int n_in,
                              void* d_out, int out_size, void* d_ws, size_t ws_size,
                              hipStream_t stream) {
    const float* x = (const float*)d_in[0];
    const int* ei  = (const int*)d_in[1];
    const int* et  = (const int*)d_in[2];
    const int E = in_sizes[2];
    const int* src  = ei;
    const int* dstp = ei + E;

    // workspace layout:
    //   inv    @ 0           (2,000,000)
    //   rowptr @ 2,097,152   (2,000,004)
    //   esrc   @ 4,194,304   (6,400,000)
    //   xbA    @ 10,616,832  (25,600,000)
    //   xbB    @ 36,306,944  (25,600,000)
    //   agg    @ 61,997,056  (CL*1280 bytes)  [cnt/cursor/bsum alias here]
    //   Bt     @ 61,997,056 + CL*1280 (589,824)
    int CL = 25000;
    if (ws_size >= 61997056ull + 100000ull * 1280ull + 589824ull) CL = 100000;
    else if (ws_size >= 61997056ull + 50000ull * 1280ull + 589824ull) CL = 50000;
    const int NCHUNK = N_NODES_C / CL;

    char* ws = (char*)d_ws;
    float* inv             = (float*)ws;
    int*   rowptr          = (int*)(ws + 2097152);
    int*   esrc            = (int*)(ws + 4194304);
    unsigned short* xbA    = (unsigned short*)(ws + 10616832);
    unsigned short* xbB    = (unsigned short*)(ws + 36306944);
    unsigned short* agg    = (unsigned short*)(ws + 61997056);
    unsigned short* BtAll  = (unsigned short*)(ws + 61997056 + (size_t)CL * 1280ull);
    int*   cnt    = (int*)(ws + 61997056);             // alias agg (dead before gathers)
    int*   cursor = (int*)(ws + 61997056 + 2097152);   // alias agg
    int*   bsum   = (int*)(ws + 61997056 + 4194304);   // alias agg

    const int nscan_blocks = (N_TOT + 255) / 256;

    hipMemsetAsync(cnt, 0, (size_t)N_TOT * 4, stream);
    count_part<<<NPART, 256, 0, stream>>>(dstp, et, cnt, E);
    make_inv<<<(N_TOT + 255) / 256, 256, 0, stream>>>(cnt, inv, N_TOT);
    scan_block<<<nscan_blocks, 256, 0, stream>>>(cnt, rowptr, bsum, N_TOT);
    scan_bsum<<<1, 256, 0, stream>>>(bsum, nscan_blocks);
    scan_add<<<nscan_blocks, 256, 0, stream>>>(rowptr, bsum, N_TOT, E);
    hipMemcpyAsync(cursor, rowptr, (size_t)N_TOT * 4, hipMemcpyDeviceToDevice, stream);
    fill_part<<<NPART, 256, 0, stream>>>(src, dstp, et, cursor, esrc, E);

    const int n4 = N_NODES_C * FEAT / 4;
    convert_x<<<(n4 + 255) / 256, 256, 0, stream>>>(x, xbA, n4);

    const float* Wp[3] = {(const float*)d_in[3], (const float*)d_in[6], (const float*)d_in[9]};
    const float* Rp[3] = {(const float*)d_in[4], (const float*)d_in[7], (const float*)d_in[10]};
    const float* Bp[3] = {(const float*)d_in[5], (const float*)d_in[8], (const float*)d_in[11]};

    const int nw = FEAT * KTOT;
    for (int l = 0; l < 3; l++)
        convert_w<<<(nw + 255) / 256, 256, 0, stream>>>(Rp[l], Wp[l],
                                                        BtAll + (size_t)l * nw);

    const int gemm_grid = (CL + BM - 1) / BM;
    dim3 ggrid((CL + 15) / 16, N_REL_C);

    // layer dataflow (bf16 ping-pong): xbA -> xbB -> xbA -> d_out(fp32)
    for (int l = 0; l < 3; l++) {
        const unsigned short* hin = (l == 1) ? xbB : xbA;
        unsigned short* outb = (l == 0) ? xbB : ((l == 1) ? xbA : nullptr);
        float* outf = (l == 2) ? (float*)d_out : nullptr;
        for (int c = 0; c < NCHUNK; c++) {
            gather_mean<<<ggrid, 256, 0, stream>>>(hin, esrc, rowptr, inv, agg,
                                                   c * CL, CL);
            rgcn_gemm<<<gemm_grid, 256, 0, stream>>>(hin, agg, BtAll + (size_t)l * nw,
                                                     Bp[l], outf, outb, c * CL, CL);
        }
    }
}

// Round 13
// 644.684 us; speedup vs baseline: 1.6274x; 1.0099x over previous
//
#include <hip/hip_runtime.h>

#define N_NODES_C 100000
#define N_REL_C 5
#define N_TOT (N_REL_C * N_NODES_C)
#define FEAT 128
#define KTOT 768        // virtual K = 128 (root) + 5*128 (relations)
#define BM 128          // GEMM block rows
#define GBK 64          // GEMM K-tile
#define NPART 2048      // blocks for XCD-partitioned count/fill (multiple of 8)

typedef __attribute__((ext_vector_type(8))) short bf16x8;
typedef __attribute__((ext_vector_type(4))) float f32x4;

__device__ inline unsigned short f2bf(float f) {
    union { float f; unsigned int u; } v; v.f = f;
    return (unsigned short)((v.u + 0x7FFFu + ((v.u >> 16) & 1u)) >> 16);
}

// packed f32x2 -> bf16x2 (RNE) in one VALU instr
__device__ __forceinline__ unsigned int cvt_pk_bf16(float lo, float hi) {
    unsigned int r;
    asm("v_cvt_pk_bf16_f32 %0, %1, %2" : "=v"(r) : "v"(lo), "v"(hi));
    return r;
}

// async 16B global->LDS: lds dest = wave-uniform base + lane*16 (m97 pattern)
__device__ __forceinline__ void g2l16(const void* g, void* l) {
    __builtin_amdgcn_global_load_lds((const __attribute__((address_space(1))) unsigned int*)g,
                                     (__attribute__((address_space(3))) unsigned int*)l,
                                     16, 0, 0);
}

// unpack 8 bf16 (uint4) into 4 float2 accumulators via vector adds.
// float2 += compiles to v_pk_add_f32 (VOP3P) on gfx950 when clang packs;
// worst case it stays 2 scalar adds (same as v10) -- no regression risk.
__device__ __forceinline__ void accp(float2 (&a)[4], uint4 u) {
    union { unsigned int u; float f; } t;
    float2 v;
    t.u = u.x << 16;         v.x = t.f;
    t.u = u.x & 0xFFFF0000u; v.y = t.f;
    a[0] += v;
    t.u = u.y << 16;         v.x = t.f;
    t.u = u.y & 0xFFFF0000u; v.y = t.f;
    a[1] += v;
    t.u = u.z << 16;         v.x = t.f;
    t.u = u.z & 0xFFFF0000u; v.y = t.f;
    a[2] += v;
    t.u = u.w << 16;         v.x = t.f;
    t.u = u.w & 0xFFFF0000u; v.y = t.f;
    a[3] += v;
}

// ---------------------------------------------------------------------------
// preprocessing: key prepass -> partitioned count -> fused scan/inv -> fill
// Key-cache (v12): key[e] computed once; the 8-class XCD-partitioned passes
// (R10: atomics/lines owned by one XCD each) re-read 4B/edge instead of 8B,
// halving the 16x re-scan traffic. make_inv fused into scan_block; scan_add
// writes cursor directly (memcpy removed); convert_w single launch.
// ---------------------------------------------------------------------------
__global__ __launch_bounds__(256) void prep_key(const int* __restrict__ dst,
                                                const int* __restrict__ et,
                                                int* __restrict__ key, int E) {
    int e = blockIdx.x * 256 + threadIdx.x;
    if (e < E) key[e] = et[e] * N_NODES_C + dst[e];
}

__global__ __launch_bounds__(256) void count_part(const int* __restrict__ key,
                                                  int* __restrict__ cnt, int E) {
    int cls = blockIdx.x & 7;
    int base = (blockIdx.x >> 3) * 256 + threadIdx.x;
    int stride = (gridDim.x >> 3) << 8;
    for (int e = base; e < E; e += stride) {
        int k = key[e];
        if ((k >> 16) == cls) atomicAdd(&cnt[k], 1);
    }
}

__global__ __launch_bounds__(256) void fill_part(const int* __restrict__ src,
                                                 const int* __restrict__ key,
                                                 int* __restrict__ cursor,
                                                 int* __restrict__ esrc, int E) {
    int cls = blockIdx.x & 7;
    int base = (blockIdx.x >> 3) * 256 + threadIdx.x;
    int stride = (gridDim.x >> 3) << 8;
    for (int e = base; e < E; e += stride) {
        int k = key[e];
        if ((k >> 16) == cls) {
            int pos = atomicAdd(&cursor[k], 1);
            esrc[pos] = src[e];
        }
    }
}

// block-level exclusive scan of cnt; also emits inv = 1/max(cnt,1) (fused)
__global__ __launch_bounds__(256) void scan_block(const int* __restrict__ cnt,
                                                  int* __restrict__ rowptr,
                                                  int* __restrict__ bsum,
                                                  float* __restrict__ inv, int n) {
    __shared__ int sh[256];
    int tid = threadIdx.x;
    int i = blockIdx.x * 256 + tid;
    int v = (i < n) ? cnt[i] : 0;
    if (i < n) inv[i] = 1.0f / (float)(v > 1 ? v : 1);
    sh[tid] = v;
    __syncthreads();
#pragma unroll
    for (int o = 1; o < 256; o <<= 1) {
        int t = (tid >= o) ? sh[tid - o] : 0;
        __syncthreads();
        sh[tid] += t;
        __syncthreads();
    }
    if (i < n) rowptr[i] = sh[tid] - v;
    if (tid == 255) bsum[blockIdx.x] = sh[255];
}

__global__ __launch_bounds__(256) void scan_bsum(int* __restrict__ bsum, int nb) {
    __shared__ int sh[256];
    __shared__ int carry;
    int tid = threadIdx.x;
    if (tid == 0) carry = 0;
    __syncthreads();
    for (int base = 0; base < nb; base += 256) {
        int i = base + tid;
        int v = (i < nb) ? bsum[i] : 0;
        sh[tid] = v;
        __syncthreads();
#pragma unroll
        for (int o = 1; o < 256; o <<= 1) {
            int t = (tid >= o) ? sh[tid - o] : 0;
            __syncthreads();
            sh[tid] += t;
            __syncthreads();
        }
        int excl = sh[tid] - v + carry;
        int chunk_total = sh[255];
        __syncthreads();
        if (i < nb) bsum[i] = excl;
        if (tid == 0) carry += chunk_total;
        __syncthreads();
    }
}

// adds block offsets; writes cursor copy too (replaces hipMemcpyAsync)
__global__ __launch_bounds__(256) void scan_add(int* __restrict__ rowptr,
                                                int* __restrict__ cursor,
                                                const int* __restrict__ bsum,
                                                int n, int Etot) {
    int i = blockIdx.x * 256 + threadIdx.x;
    if (i < n) {
        int v = rowptr[i] + bsum[blockIdx.x];
        rowptr[i] = v;
        cursor[i] = v;
    }
    if (i == 0) rowptr[n] = Etot;
}

// ---------------------------------------------------------------------------
// conversions to bf16
// ---------------------------------------------------------------------------
__global__ __launch_bounds__(256) void convert_x(const float* __restrict__ x,
                                                 unsigned short* __restrict__ xb, int n4) {
    int i = blockIdx.x * 256 + threadIdx.x;
    if (i >= n4) return;
    float4 v = ((const float4*)x)[i];
    ushort4 o;
    o.x = f2bf(v.x); o.y = f2bf(v.y); o.z = f2bf(v.z); o.w = f2bf(v.w);
    ((ushort4*)xb)[i] = o;
}

// Bt[c][kv] per layer (col-major over virtual K); all 3 layers in one launch
__global__ __launch_bounds__(256) void convert_w3(const float* __restrict__ r0,
                                                  const float* __restrict__ w0,
                                                  const float* __restrict__ r1,
                                                  const float* __restrict__ w1,
                                                  const float* __restrict__ r2,
                                                  const float* __restrict__ w2,
                                                  unsigned short* __restrict__ BtAll) {
    int idx = blockIdx.x * 256 + threadIdx.x;
    if (idx >= FEAT * KTOT) return;
    int l = blockIdx.y;
    const float* root = (l == 0) ? r0 : ((l == 1) ? r1 : r2);
    const float* W    = (l == 0) ? w0 : ((l == 1) ? w1 : w2);
    int c = idx / KTOT;
    int kv = idx - c * KTOT;
    float val;
    if (kv < FEAT) {
        val = root[kv * FEAT + c];
    } else {
        int r = (kv - FEAT) >> 7;
        int kk = (kv - FEAT) & 127;
        val = W[((size_t)r * FEAT + kk) * FEAT + c];
    }
    BtAll[(size_t)l * FEAT * KTOT + idx] = f2bf(val);
}

// ---------------------------------------------------------------------------
// gather: agg[r][local][:] = mean over CSR[r][node] of hb[src][:]  (bf16 out)
// R7-verified structure (77us = fabric floor; FETCH 187MB = hb x 8 XCDs):
// quarter-wave per (relation, node), x4 unroll, float2 packed accumulate
// (v12: v_pk_add_f32 candidate), cvt_pk epilogue.
// ---------------------------------------------------------------------------
__global__ __launch_bounds__(256) void gather_mean(const unsigned short* __restrict__ hb,
                                                   const int* __restrict__ esrc,
                                                   const int* __restrict__ rowptr,
                                                   const float* __restrict__ inv,
                                                   unsigned short* __restrict__ agg,
                                                   int chunk0, int CL) {
    int qw = threadIdx.x >> 4;       // 0..15 quarter-waves per block
    int seg = threadIdx.x & 15;      // feats [seg*8, seg*8+8)
    int local = blockIdx.x * 16 + qw;
    if (local >= CL) return;
    int r = blockIdx.y;
    int node = chunk0 + local;
    int lo = rowptr[r * N_NODES_C + node];
    int hi = rowptr[r * N_NODES_C + node + 1];

    float2 a0[4], a1[4];
#pragma unroll
    for (int j = 0; j < 4; j++) {
        a0[j] = make_float2(0.f, 0.f);
        a1[j] = make_float2(0.f, 0.f);
    }

    const unsigned short* hseg = hb + seg * 8;

    int e = lo;
    for (; e + 4 <= hi; e += 4) {
        int s0 = esrc[e];
        int s1 = esrc[e + 1];
        int s2 = esrc[e + 2];
        int s3 = esrc[e + 3];
        uint4 u0 = *(const uint4*)(hseg + ((size_t)s0 << 7));
        uint4 u1 = *(const uint4*)(hseg + ((size_t)s1 << 7));
        uint4 u2 = *(const uint4*)(hseg + ((size_t)s2 << 7));
        uint4 u3 = *(const uint4*)(hseg + ((size_t)s3 << 7));
        accp(a0, u0);
        accp(a1, u1);
        accp(a0, u2);
        accp(a1, u3);
    }
    if (e + 2 <= hi) {
        int s0 = esrc[e];
        int s1 = esrc[e + 1];
        uint4 u0 = *(const uint4*)(hseg + ((size_t)s0 << 7));
        uint4 u1 = *(const uint4*)(hseg + ((size_t)s1 << 7));
        accp(a0, u0);
        accp(a1, u1);
        e += 2;
    }
    if (e < hi) {
        int s = esrc[e];
        uint4 u = *(const uint4*)(hseg + ((size_t)s << 7));
        accp(a0, u);
    }

    float sc = inv[r * N_NODES_C + node];
    float2 s;
    uint4 o;
    s.x = a0[0].x + a1[0].x; s.y = a0[0].y + a1[0].y;
    o.x = cvt_pk_bf16(s.x * sc, s.y * sc);
    s.x = a0[1].x + a1[1].x; s.y = a0[1].y + a1[1].y;
    o.y = cvt_pk_bf16(s.x * sc, s.y * sc);
    s.x = a0[2].x + a1[2].x; s.y = a0[2].y + a1[2].y;
    o.z = cvt_pk_bf16(s.x * sc, s.y * sc);
    s.x = a0[3].x + a1[3].x; s.y = a0[3].y + a1[3].y;
    o.w = cvt_pk_bf16(s.x * sc, s.y * sc);
    *(uint4*)(agg + (((size_t)r * CL + local) << 7) + seg * 8) = o;
}

// ---------------------------------------------------------------------------
// MFMA GEMM (m97-style): C[n][0:128] = relu( A_virt[n][0:768] @ B + bias )
//   A_virt k<128 -> hb[node][k]; k>=128 -> agg[r][local][k%128] (pre-scaled means)
// BK=64, global_load_lds(16B) staging into unpadded LDS with chunk-XOR swizzle
// (c ^ (row&7)); reader applies same XOR -> 2-way bank aliasing (free, m136).
// Block 128x128, 4 waves 2x2, wave tile 64x64 (4x4 MFMA 16x16x32 tiles).
// ---------------------------------------------------------------------------
__global__ __launch_bounds__(256) void rgcn_gemm(const unsigned short* __restrict__ hb,
                                                 const unsigned short* __restrict__ agg,
                                                 const unsigned short* __restrict__ Bt,
                                                 const float* __restrict__ bias,
                                                 float* __restrict__ outf,
                                                 unsigned short* __restrict__ outb,
                                                 int chunk0, int CL) {
    __shared__ unsigned short As[BM * GBK];    // 16 KB
    __shared__ unsigned short Bs[FEAT * GBK];  // 16 KB

    const int tid = threadIdx.x;
    const int w = tid >> 6, lane = tid & 63;
    const int wr = w >> 1, wc = w & 1;
    const int lm = lane & 15, lq = lane >> 4;
    const int brow0 = blockIdx.x * BM;

    f32x4 acc[4][4];
#pragma unroll
    for (int i = 0; i < 4; i++)
#pragma unroll
        for (int j = 0; j < 4; j++) acc[i][j] = (f32x4){0.f, 0.f, 0.f, 0.f};

    // staging geometry: 1024 16B-chunks per tile; instr i of wave w covers
    // chunk ids cid = (w*4+i)*64 + lane; cid -> (row = cid>>3, c = cid&7).
    // source chunk is XOR-swizzled: cs = c ^ (row&7).
    size_t hboff[4];   // hb row offset + swizzled chunk (add kb)
    size_t aggoff[4];  // agg row offset + swizzled chunk (add rel term)
    size_t boff[4];    // Bt col offset + swizzled chunk (add kb)
    int ldsbase[4];    // wave-uniform LDS ushort base per instr
#pragma unroll
    for (int i = 0; i < 4; i++) {
        int cid = (w * 4 + i) * 64 + lane;
        int row = cid >> 3;
        int cs = (cid & 7) ^ (row & 7);
        int gr = brow0 + row;
        if (gr >= CL) gr = CL - 1;
        hboff[i]  = ((size_t)(chunk0 + gr) << 7) + cs * 8;
        aggoff[i] = ((size_t)gr << 7) + cs * 8;
        boff[i]   = (size_t)row * KTOT + cs * 8;   // row doubles as col for B
        ldsbase[i] = ((w * 4 + i) * 64) * 8;
    }

    for (int kb = 0; kb < KTOT; kb += GBK) {
        __syncthreads();   // prev-iter LDS reads done before overwrite
        if (kb < FEAT) {
#pragma unroll
            for (int i = 0; i < 4; i++)
                g2l16(hb + hboff[i] + kb, &As[ldsbase[i]]);
        } else {
            size_t reloff = (((size_t)((kb - FEAT) >> 7)) * CL << 7) + (size_t)((kb - FEAT) & 127);
#pragma unroll
            for (int i = 0; i < 4; i++)
                g2l16(agg + aggoff[i] + reloff, &As[ldsbase[i]]);
        }
#pragma unroll
        for (int i = 0; i < 4; i++)
            g2l16(Bt + boff[i] + kb, &Bs[ldsbase[i]]);
        __syncthreads();   // compiler emits vmcnt(0) drain before barrier

#pragma unroll
        for (int h = 0; h < 2; h++) {
            bf16x8 af[4], bf[4];
#pragma unroll
            for (int t = 0; t < 4; t++) {
                int row = wr * 64 + t * 16 + lm;
                int ca = (h * 4 + lq) ^ (row & 7);
                af[t] = *(const bf16x8*)&As[row * GBK + ca * 8];
                int col = wc * 64 + t * 16 + lm;
                int cb = (h * 4 + lq) ^ (col & 7);
                bf[t] = *(const bf16x8*)&Bs[col * GBK + cb * 8];
            }
#pragma unroll
            for (int i = 0; i < 4; i++)
#pragma unroll
                for (int j = 0; j < 4; j++)
                    acc[i][j] = __builtin_amdgcn_mfma_f32_16x16x32_bf16(af[i], bf[j], acc[i][j], 0, 0, 0);
        }
    }

    float bcol[4];
#pragma unroll
    for (int j = 0; j < 4; j++) bcol[j] = bias[wc * 64 + j * 16 + lm];

#pragma unroll
    for (int i = 0; i < 4; i++) {
#pragma unroll
        for (int reg = 0; reg < 4; reg++) {
            int lr = brow0 + wr * 64 + i * 16 + lq * 4 + reg;
            if (lr < CL) {
                size_t grow = (size_t)(chunk0 + lr) << 7;
#pragma unroll
                for (int j = 0; j < 4; j++) {
                    float v = acc[i][j][reg] + bcol[j];
                    v = fmaxf(v, 0.f);
                    int col = wc * 64 + j * 16 + lm;
                    if (outf) outf[grow + col] = v;
                    else outb[grow + col] = f2bf(v);
                }
            }
        }
    }
}

// ---------------------------------------------------------------------------
extern "C" void kernel_launch(void* const* d_in, const int* in_sizes, int n_in,
                              void* d_out, int out_size, void* d_ws, size_t ws_size,
                              hipStream_t stream) {
    const float* x = (const float*)d_in[0];
    const int* ei  = (const int*)d_in[1];
    const int* et  = (const int*)d_in[2];
    const int E = in_sizes[2];
    const int* src  = ei;
    const int* dstp = ei + E;

    // workspace layout:
    //   inv    @ 0           (2,000,000)
    //   rowptr @ 2,097,152   (2,000,004)
    //   esrc   @ 4,194,304   (6,400,000)
    //   xbA    @ 10,616,832  (25,600,000)
    //   xbB    @ 36,306,944  (25,600,000)
    //   agg    @ 61,997,056  (CL*1280 bytes)  [cnt/cursor/bsum/key alias here]
    //   Bt     @ 61,997,056 + CL*1280 (1,769,472 = 3 layers)
    int CL = 25000;
    if (ws_size >= 61997056ull + 100000ull * 1280ull + 1769472ull) CL = 100000;
    else if (ws_size >= 61997056ull + 50000ull * 1280ull + 1769472ull) CL = 50000;
    const int NCHUNK = N_NODES_C / CL;

    char* ws = (char*)d_ws;
    float* inv             = (float*)ws;
    int*   rowptr          = (int*)(ws + 2097152);
    int*   esrc            = (int*)(ws + 4194304);
    unsigned short* xbA    = (unsigned short*)(ws + 10616832);
    unsigned short* xbB    = (unsigned short*)(ws + 36306944);
    unsigned short* agg    = (unsigned short*)(ws + 61997056);
    unsigned short* BtAll  = (unsigned short*)(ws + 61997056 + (size_t)CL * 1280ull);
    int*   cnt    = (int*)(ws + 61997056);             // alias agg (dead before gathers)
    int*   cursor = (int*)(ws + 61997056 + 2097152);   // alias agg
    int*   bsum   = (int*)(ws + 61997056 + 4194304);   // alias agg
    int*   key    = (int*)(ws + 61997056 + 8388608);   // alias agg (6.4MB)

    const int nscan_blocks = (N_TOT + 255) / 256;

    hipMemsetAsync(cnt, 0, (size_t)N_TOT * 4, stream);
    prep_key<<<(E + 255) / 256, 256, 0, stream>>>(dstp, et, key, E);
    count_part<<<NPART, 256, 0, stream>>>(key, cnt, E);
    scan_block<<<nscan_blocks, 256, 0, stream>>>(cnt, rowptr, bsum, inv, N_TOT);
    scan_bsum<<<1, 256, 0, stream>>>(bsum, nscan_blocks);
    scan_add<<<nscan_blocks, 256, 0, stream>>>(rowptr, cursor, bsum, N_TOT, E);
    fill_part<<<NPART, 256, 0, stream>>>(src, key, cursor, esrc, E);

    const int n4 = N_NODES_C * FEAT / 4;
    convert_x<<<(n4 + 255) / 256, 256, 0, stream>>>(x, xbA, n4);

    const int nw = FEAT * KTOT;
    convert_w3<<<dim3((nw + 255) / 256, 3), 256, 0, stream>>>(
        (const float*)d_in[4], (const float*)d_in[3],
        (const float*)d_in[7], (const float*)d_in[6],
        (const float*)d_in[10], (const float*)d_in[9], BtAll);

    const float* Bp[3] = {(const float*)d_in[5], (const float*)d_in[8], (const float*)d_in[11]};

    const int gemm_grid = (CL + BM - 1) / BM;
    dim3 ggrid((CL + 15) / 16, N_REL_C);

    // layer dataflow (bf16 ping-pong): xbA -> xbB -> xbA -> d_out(fp32)
    for (int l = 0; l < 3; l++) {
        const unsigned short* hin = (l == 1) ? xbB : xbA;
        unsigned short* outb = (l == 0) ? xbB : ((l == 1) ? xbA : nullptr);
        float* outf = (l == 2) ? (float*)d_out : nullptr;
        for (int c = 0; c < NCHUNK; c++) {
            gather_mean<<<ggrid, 256, 0, stream>>>(hin, esrc, rowptr, inv, agg,
                                                   c * CL, CL);
            rgcn_gemm<<<gemm_grid, 256, 0, stream>>>(hin, agg, BtAll + (size_t)l * nw,
                                                     Bp[l], outf, outb, c * CL, CL);
        }
    }
}